// Round 4
// baseline (232.687 us; speedup 1.0000x reference)
//
#include <hip/hip_runtime.h>
#include <hip/hip_cooperative_groups.h>
#include <cstdint>
#include <cstddef>

#define NB 16
#define NC 256
#define NN 4096
#define ND 256

typedef unsigned short u16;
typedef unsigned int u32;

typedef __attribute__((ext_vector_type(8))) short short8;
typedef __attribute__((ext_vector_type(4))) float f32x4;

__device__ __forceinline__ u16 f2bf(float f) {
  union { float f; u32 u; } v; v.f = f;
  u32 r = v.u + 0x7FFFu + ((v.u >> 16) & 1u);
  return (u16)(r >> 16);
}
__device__ __forceinline__ float bf2f(u16 h) {
  union { u32 u; float f; } v; v.u = ((u32)h) << 16; return v.f;
}

// ---------------------------------------------------------------------------
// Single cooperative kernel. Grid = 256 blocks (1/CU) x 512 threads.
// Block g -> (b = g>>4, n-chunk j = g&15, n0 = j*256). LDS holds the block's
// bf16 x tile [256 n][256 c] (128 KiB, XOR-swizzled in 16B chunks:
// phys_chunk = chunk ^ (n&7) ^ ((n>>3)&7)) and stays resident across the
// grid-wide softmax barrier -- x is read from HBM exactly once, xbT never
// materialized.
//  P1: load x (coalesced float4, reg-transpose) -> LDS; q[n] reduce; chunk
//      softmax (m,l); pacc[c] = sum_n bf16(x)*e^{q-m}; Wv bf16 cast (g<16).
//      threadfence + grid.sync (producer release; readers first-touch after).
//  P2: every block redundantly combines its b's 16 partials -> xs -> ctx
//      (16KB L2 reads; no second sync needed).
//  P3: MFMA 16x16x32 GEMM: A = wvb short8 from global (L2-hot), B = LDS tile.
//      out = relu(acc)*ctx. Wave tile 64d x 128n, acc[4][8] f32x4.
// ---------------------------------------------------------------------------
__global__ __launch_bounds__(512) void k_mono(const float* __restrict__ x,
                                              const float* __restrict__ W,
                                              float* __restrict__ out,
                                              float* __restrict__ pacc,
                                              float* __restrict__ pm,
                                              float* __restrict__ pl,
                                              u16* __restrict__ wvb) {
  namespace cg = cooperative_groups;
  cg::grid_group grid = cg::this_grid();

  __shared__ __align__(16) u16 xt[256 * 256];     // 131,072 B, swizzled
  __shared__ float qred[16 * 257];                //  16,448 B
  __shared__ float pv[256];                       //   1,024 B
  __shared__ float pp2[2 * 257];                  //   2,056 B
  __shared__ float am[16], al[16];                //     128 B
  __shared__ float sx[256];                       //   1,024 B
  __shared__ float sctx[256];                     //   1,024 B
  __shared__ float wredm[8], wredl[8];            //      64 B

  const int t = threadIdx.x;
  const int g = blockIdx.x;
  const int b = g >> 4;
  const int n0 = (g & 15) << 8;

  // ---------------- Phase 1: load + transpose + q + chunk softmax ----------
  const int tx = t & 31;           // n-group (8 n each)
  const int ty = t >> 5;           // c-group 0..15 (8 c each, x2 halves)
  const int nl = tx * 8;

  float qp[8] = {0.f, 0.f, 0.f, 0.f, 0.f, 0.f, 0.f, 0.f};

  for (int i = 0; i < 2; ++i) {
    const int c0 = ty * 8 + i * 128;
    const float4 w0 = *(const float4*)(W + c0);
    const float4 w1 = *(const float4*)(W + c0 + 4);
    const float wq[8] = {w0.x, w0.y, w0.z, w0.w, w1.x, w1.y, w1.z, w1.w};
    short8 pk[8];
#pragma unroll
    for (int r = 0; r < 8; ++r) {
      const float* xr = x + (size_t)(b * NC + c0 + r) * NN + n0 + nl;
      const float4 va = *(const float4*)(xr);
      const float4 vb = *(const float4*)(xr + 4);
      qp[0] += wq[r] * va.x; qp[1] += wq[r] * va.y;
      qp[2] += wq[r] * va.z; qp[3] += wq[r] * va.w;
      qp[4] += wq[r] * vb.x; qp[5] += wq[r] * vb.y;
      qp[6] += wq[r] * vb.z; qp[7] += wq[r] * vb.w;
      pk[0][r] = (short)f2bf(va.x); pk[1][r] = (short)f2bf(va.y);
      pk[2][r] = (short)f2bf(va.z); pk[3][r] = (short)f2bf(va.w);
      pk[4][r] = (short)f2bf(vb.x); pk[5][r] = (short)f2bf(vb.y);
      pk[6][r] = (short)f2bf(vb.z); pk[7][r] = (short)f2bf(vb.w);
    }
    const int chunk = ty + i * 16;
#pragma unroll
    for (int jn = 0; jn < 8; ++jn) {
      const int n = nl + jn;
      const int phys = chunk ^ (n & 7) ^ ((n >> 3) & 7);
      *(short8*)&xt[n * 256 + phys * 8] = pk[jn];
    }
  }

#pragma unroll
  for (int jn = 0; jn < 8; ++jn) qred[ty * 257 + nl + jn] = qp[jn];
  __syncthreads();

  // q[n] for n = t (t<256); block softmax over the 256-n chunk
  float q = 0.f;
  if (t < 256) {
#pragma unroll
    for (int k = 0; k < 16; ++k) q += qred[k * 257 + t];
  }
  float wm = (t < 256) ? q : -3.4e38f;
#pragma unroll
  for (int off = 1; off < 64; off <<= 1) wm = fmaxf(wm, __shfl_xor(wm, off));
  const int wvn = t >> 6;
  if ((t & 63) == 0 && wvn < 4) wredm[wvn] = wm;
  __syncthreads();
  const float M = fmaxf(fmaxf(wredm[0], wredm[1]), fmaxf(wredm[2], wredm[3]));
  float p = 0.f;
  if (t < 256) { p = __expf(q - M); pv[t] = p; }
  float wl = (t < 256) ? p : 0.f;
#pragma unroll
  for (int off = 1; off < 64; off <<= 1) wl += __shfl_xor(wl, off);
  if ((t & 63) == 0 && wvn < 4) wredl[wvn] = wl;
  __syncthreads();
  const float Lc = wredl[0] + wredl[1] + wredl[2] + wredl[3];

  // pacc[c] = sum_n bf16(x[c][n]) * p[n]  (column reads: 2 lanes/bank, free)
  {
    const int cc = t & 255, hh = t >> 8;
    const int cchunk = cc >> 3, clo = cc & 7;
    float aps = 0.f;
#pragma unroll 8
    for (int nn2 = 0; nn2 < 128; ++nn2) {
      const int n = hh * 128 + nn2;
      const int phys = cchunk ^ (n & 7) ^ ((n >> 3) & 7);
      aps += bf2f(xt[n * 256 + phys * 8 + clo]) * pv[n];
    }
    pp2[hh * 257 + cc] = aps;
  }
  __syncthreads();
  if (t < 256) pacc[(size_t)g * 256 + t] = pp2[t] + pp2[257 + t];
  if (t == 0) { pm[g] = M; pl[g] = Lc; }

  // Wv bf16 cast: blocks 0..15, 16 rows each (fully coalesced)
  if (g < 16) {
    const float* wsrc = W + (size_t)(1 + ND) * NC + (size_t)g * 16 * NC;
    const int idx = t * 8;
    const float4 a0 = *(const float4*)(wsrc + idx);
    const float4 a1 = *(const float4*)(wsrc + idx + 4);
    short8 o;
    o[0] = (short)f2bf(a0.x); o[1] = (short)f2bf(a0.y);
    o[2] = (short)f2bf(a0.z); o[3] = (short)f2bf(a0.w);
    o[4] = (short)f2bf(a1.x); o[5] = (short)f2bf(a1.y);
    o[6] = (short)f2bf(a1.z); o[7] = (short)f2bf(a1.w);
    *(short8*)(wvb + (size_t)g * 4096 + idx) = o;
  }

  __threadfence();
  grid.sync();
  __threadfence();

  // ---------------- Phase 2: combine partials -> xs -> ctx (per block) -----
  if (t < 16) { am[t] = pm[b * 16 + t]; al[t] = pl[b * 16 + t]; }
  __syncthreads();
  float M2 = -3.4e38f;
#pragma unroll
  for (int i = 0; i < 16; ++i) M2 = fmaxf(M2, am[i]);
  if (t < 256) {
    float xsv = 0.f, L2s = 0.f;
#pragma unroll
    for (int i = 0; i < 16; ++i) {
      const float wgt = __expf(am[i] - M2);
      L2s += wgt * al[i];
      xsv += wgt * pacc[(size_t)(b * 16 + i) * 256 + t];
    }
    sx[t] = xsv / L2s;
  }
  __syncthreads();
  if (t < 256) {
    const float* wk = W + (size_t)(1 + t) * NC;
    float a = 0.f;
#pragma unroll 4
    for (int c4 = 0; c4 < 64; ++c4) {
      const float4 w4 = *(const float4*)(wk + c4 * 4);
      const float4 s4 = *(const float4*)&sx[c4 * 4];
      a += w4.x * s4.x + w4.y * s4.y + w4.z * s4.z + w4.w * s4.w;
    }
    sctx[t] = a;
  }
  __syncthreads();

  // ---------------- Phase 3: GEMM out = relu(Wv @ x) * ctx -----------------
  const int lane = t & 63, w = t >> 6;
  const int wd = (w >> 1) * 64, wn = (w & 1) * 128;
  const int quad = lane >> 4, l15 = lane & 15;

  f32x4 acc[4][8];
#pragma unroll
  for (int mi = 0; mi < 4; ++mi)
#pragma unroll
    for (int ni = 0; ni < 8; ++ni)
      acc[mi][ni] = (f32x4){0.f, 0.f, 0.f, 0.f};

#pragma unroll
  for (int kq = 0; kq < 8; ++kq) {
    short8 af[4];
#pragma unroll
    for (int mi = 0; mi < 4; ++mi)
      af[mi] = *(const short8*)(wvb + (size_t)(wd + mi * 16 + l15) * NC +
                                kq * 32 + quad * 8);
    short8 bfr[8];
#pragma unroll
    for (int ni = 0; ni < 8; ++ni) {
      const int n = wn + ni * 16 + l15;
      const int phys = (kq * 4 + quad) ^ (n & 7) ^ ((n >> 3) & 7);
      bfr[ni] = *(const short8*)&xt[n * 256 + phys * 8];
    }
#pragma unroll
    for (int mi = 0; mi < 4; ++mi)
#pragma unroll
      for (int ni = 0; ni < 8; ++ni)
        acc[mi][ni] = __builtin_amdgcn_mfma_f32_16x16x32_bf16(af[mi], bfr[ni],
                                                              acc[mi][ni], 0, 0, 0);
  }

#pragma unroll
  for (int mi = 0; mi < 4; ++mi) {
#pragma unroll
    for (int r = 0; r < 4; ++r) {
      const int d = wd + mi * 16 + quad * 4 + r;
      const float cx = sctx[d];
      float* op = out + (size_t)(b * NC + d) * NN + n0 + wn + l15;
#pragma unroll
      for (int ni = 0; ni < 8; ++ni)
        op[ni * 16] = fmaxf(acc[mi][ni][r], 0.f) * cx;
    }
  }
}

// ---------------------------------------------------------------------------
extern "C" void kernel_launch(void* const* d_in, const int* in_sizes, int n_in,
                              void* d_out, int out_size, void* d_ws, size_t ws_size,
                              hipStream_t stream) {
  const float* x = (const float*)d_in[0];
  const float* W = (const float*)d_in[1];
  float* out = (float*)d_out;

  char* ws = (char*)d_ws;
  float* pacc = (float*)ws;                       // 262,144 B
  float* pm   = (float*)(ws + 262144);            //   1,024 B
  float* pl   = (float*)(ws + 263168);            //   1,024 B
  u16* wvb    = (u16*)(ws + 264192);              // 131,072 B

  void* args[] = {(void*)&x, (void*)&W, (void*)&out,
                  (void*)&pacc, (void*)&pm, (void*)&pl, (void*)&wvb};
  hipLaunchCooperativeKernel((void*)k_mono, dim3(256), dim3(512), args, 0,
                             stream);
}

// Round 5
// 154.007 us; speedup vs baseline: 1.5109x; 1.5109x over previous
//
#include <hip/hip_runtime.h>
#include <cstdint>
#include <cstddef>

#define NB 16
#define NC 256
#define NN 4096
#define ND 256

typedef unsigned short u16;
typedef unsigned int u32;

typedef __attribute__((ext_vector_type(8))) short short8;
typedef __attribute__((ext_vector_type(4))) float f32x4;

__device__ __forceinline__ u16 f2bf(float f) {
  union { float f; u32 u; } v; v.f = f;
  u32 r = v.u + 0x7FFFu + ((v.u >> 16) & 1u);
  return (u16)(r >> 16);
}
__device__ __forceinline__ float bf2f(u16 h) {
  union { u32 u; float f; } v; v.u = ((u32)h) << 16; return v.f;
}

// ---------------------------------------------------------------------------
// Kernel 1 (round-3 verified): per (b, n-tile of 64) block spanning FULL C.
// Thread micro-tile 8c x 8n; float4 coalesced loads; register-renaming
// transpose -> short8 16B xbT stores; conflict-free LDS q-reduce; in-wave
// shfl softmax partials (m,l) and pacc; Wv bf16 cast folded into 8 blocks.
// ---------------------------------------------------------------------------
__global__ __launch_bounds__(256) void k_fuse1(const float* __restrict__ x,
                                               const float* __restrict__ W,
                                               u16* __restrict__ xbT,
                                               u16* __restrict__ wvb,
                                               float* __restrict__ pm,
                                               float* __restrict__ pl,
                                               float* __restrict__ pacc) {
  __shared__ float qred[32 * 65];   // 8,320 B, bank-conflict-free
  __shared__ float qred2[4 * 65];   // 1,040 B
  const int t = threadIdx.x;
  const int b = blockIdx.y, n0 = blockIdx.x * 64;
  const int tx = t & 7, ty = t >> 3;        // tx: n-group 0..7, ty: c-group 0..31
  const int c0 = ty * 8, nl = tx * 8;
  const float* xb = x + (size_t)b * NC * NN + n0;

  const float4 w0 = *(const float4*)(W + c0);
  const float4 w1 = *(const float4*)(W + c0 + 4);
  const float wq[8] = {w0.x, w0.y, w0.z, w0.w, w1.x, w1.y, w1.z, w1.w};

  short8 pk[8];          // pk[j] = bf16 x[c0..c0+8][nl+j]  (transposed packs)
  float qp[8] = {0.f, 0.f, 0.f, 0.f, 0.f, 0.f, 0.f, 0.f};

#pragma unroll
  for (int r = 0; r < 8; ++r) {
    const float* xr = xb + (size_t)(c0 + r) * NN + nl;
    const float4 va = *(const float4*)(xr);
    const float4 vb = *(const float4*)(xr + 4);
    qp[0] += wq[r] * va.x; qp[1] += wq[r] * va.y;
    qp[2] += wq[r] * va.z; qp[3] += wq[r] * va.w;
    qp[4] += wq[r] * vb.x; qp[5] += wq[r] * vb.y;
    qp[6] += wq[r] * vb.z; qp[7] += wq[r] * vb.w;
    pk[0][r] = (short)f2bf(va.x); pk[1][r] = (short)f2bf(va.y);
    pk[2][r] = (short)f2bf(va.z); pk[3][r] = (short)f2bf(va.w);
    pk[4][r] = (short)f2bf(vb.x); pk[5][r] = (short)f2bf(vb.y);
    pk[6][r] = (short)f2bf(vb.z); pk[7][r] = (short)f2bf(vb.w);
  }

  u16* ob = xbT + (size_t)(b * NN + n0 + nl) * NC + c0;
#pragma unroll
  for (int j = 0; j < 8; ++j)
    *(short8*)(ob + (size_t)j * NC) = pk[j];

#pragma unroll
  for (int j = 0; j < 8; ++j) qred[ty * 65 + nl + j] = qp[j];
  __syncthreads();
  {
    const int n = t & 63, g = t >> 6;
    float s = 0.f;
#pragma unroll
    for (int k = 0; k < 8; ++k) s += qred[(g * 8 + k) * 65 + n];
    qred2[g * 65 + n] = s;
  }
  __syncthreads();

  float q[8];
#pragma unroll
  for (int j = 0; j < 8; ++j)
    q[j] = qred2[0 * 65 + nl + j] + qred2[1 * 65 + nl + j] +
           qred2[2 * 65 + nl + j] + qred2[3 * 65 + nl + j];

  float m = q[0];
#pragma unroll
  for (int j = 1; j < 8; ++j) m = fmaxf(m, q[j]);
#pragma unroll
  for (int off = 1; off < 8; off <<= 1) m = fmaxf(m, __shfl_xor(m, off));

  float p[8]; float l = 0.f;
#pragma unroll
  for (int j = 0; j < 8; ++j) { p[j] = __expf(q[j] - m); l += p[j]; }
#pragma unroll
  for (int off = 1; off < 8; off <<= 1) l += __shfl_xor(l, off);

  float sc[8];
#pragma unroll
  for (int r = 0; r < 8; ++r) {
    float s = 0.f;
#pragma unroll
    for (int j = 0; j < 8; ++j) s += bf2f((u16)pk[j][r]) * p[j];
    sc[r] = s;
  }
#pragma unroll
  for (int off = 1; off < 8; off <<= 1) {
#pragma unroll
    for (int r = 0; r < 8; ++r) sc[r] += __shfl_xor(sc[r], off);
  }
  if (tx == 0) {
    float* pp = pacc + ((size_t)b * 64 + blockIdx.x) * NC + c0;
#pragma unroll
    for (int r = 0; r < 8; ++r) pp[r] = sc[r];
  }
  if (t == 0) {
    pm[b * 64 + blockIdx.x] = m;
    pl[b * 64 + blockIdx.x] = l;
  }

  if (b == 0 && blockIdx.x < 8) {
    const float* wv = W + (size_t)(1 + ND) * NC;
    const int base = blockIdx.x * 8192;
#pragma unroll
    for (int i = 0; i < 8; ++i) {
      const int idx = base + i * 1024 + t * 4;
      const float4 v = *(const float4*)(wv + idx);
      ushort4 o = {f2bf(v.x), f2bf(v.y), f2bf(v.z), f2bf(v.w)};
      *(ushort4*)(wvb + idx) = o;
    }
  }
}

// ---------------------------------------------------------------------------
// Kernel 2: fused combine + GEMM.
//  Prologue: issue K-step-0 LDS staging, then (overlapped with its HBM
//  latency) redundantly combine this b's 64 softmax partials -> xs -> ctx
//  (pacc 64KB + W via L2).
//  GEMM: bf16 MFMA 16x16x32, BM=256 (full D, xbT read once), BN=128, BK=64,
//  8 waves (4d x 2n). XOR-swizzled LDS as before.
//  Operand roles SWAPPED vs round 3: A-frag = x rows (n), B-frag = Wv rows
//  (d)  =>  D row = n, col = d  =>  each lane holds 4 consecutive n for a
//  fixed d  =>  epilogue is f32x4 16B (nontemporal) stores.
// ---------------------------------------------------------------------------
#define BM 256
#define BN 128
#define BK 64

__global__ __launch_bounds__(512) void k_gemm(const u16* __restrict__ xbT,
                                              const u16* __restrict__ wvb,
                                              const float* __restrict__ W,
                                              const float* __restrict__ pm,
                                              const float* __restrict__ pl,
                                              const float* __restrict__ pacc,
                                              float* __restrict__ out) {
  __shared__ __align__(16) u16 As[BM * BK];   // 32 KB (Wv)
  __shared__ __align__(16) u16 Bs[BN * BK];   // 16 KB (x)
  __shared__ float am[64], al[64];
  __shared__ __align__(16) float sx[NC];
  __shared__ float sctx[NC];

  const int t = threadIdx.x;
  const int b = blockIdx.y;
  const int n0 = blockIdx.x * BN;
  const int lane = t & 63, w = t >> 6;
  const int wd = (w >> 1) * 64, wn = (w & 1) * 64;
  const int quad = lane >> 4, l15 = lane & 15;

  // staging addresses (XOR swizzle on the global source, linear LDS dest)
  const int rstg = t >> 3;                               // 0..63
  const int l8 = ((t & 7) ^ (rstg & 7)) * 8;             // logical u16 offset
  const u16* gA = wvb + (size_t)rstg * NC + l8;
  const u16* gB = xbT + (size_t)(b * NN + n0 + rstg) * NC + l8;
  const int ldst = 8 * t;                                // u16 offset in LDS

  // ---- issue K-step 0 staging, then combine under its latency ----
#pragma unroll
  for (int i = 0; i < 4; ++i)
    __builtin_amdgcn_global_load_lds(
        (const __attribute__((address_space(1))) u32*)(gA + (size_t)(64 * i) * NC),
        (__attribute__((address_space(3))) u32*)(As + 4096 * i + ldst), 16, 0, 0);
#pragma unroll
  for (int i = 0; i < 2; ++i)
    __builtin_amdgcn_global_load_lds(
        (const __attribute__((address_space(1))) u32*)(gB + (size_t)(64 * i) * NC),
        (__attribute__((address_space(3))) u32*)(Bs + 4096 * i + ldst), 16, 0, 0);

  if (t < 64) { am[t] = pm[b * 64 + t]; al[t] = pl[b * 64 + t]; }
  __syncthreads();   // am/al visible; staging 0 complete (vmcnt drain)

  float M2 = -3.4e38f;
#pragma unroll
  for (int i = 0; i < 64; ++i) M2 = fmaxf(M2, am[i]);
  if (t < 256) {
    float xsv = 0.f, L2s = 0.f;
#pragma unroll 8
    for (int i = 0; i < 64; ++i) {
      const float wgt = __expf(am[i] - M2);
      L2s += wgt * al[i];
      xsv += wgt * pacc[(size_t)(b * 64 + i) * NC + t];
    }
    sx[t] = xsv / L2s;
  }
  __syncthreads();   // sx ready
  if (t < 256) {
    const float* wk = W + (size_t)(1 + t) * NC;
    float a = 0.f;
#pragma unroll 4
    for (int c4 = 0; c4 < 64; ++c4) {
      const float4 w4 = *(const float4*)(wk + c4 * 4);
      const float4 s4 = *(const float4*)&sx[c4 * 4];
      a += w4.x * s4.x + w4.y * s4.y + w4.z * s4.z + w4.w * s4.w;
    }
    sctx[t] = a;     // visibility guaranteed by K-loop barriers
  }

  // ---- GEMM main loop (single-buffered, staging for kk>0 inside) ----
  f32x4 acc[4][4];   // acc[ni][mi]: ni = n-subtile, mi = d-subtile
#pragma unroll
  for (int ni = 0; ni < 4; ++ni)
#pragma unroll
    for (int mi = 0; mi < 4; ++mi)
      acc[ni][mi] = (f32x4){0.f, 0.f, 0.f, 0.f};

  const int pq0 = ((0 * 4 + quad) ^ (l15 & 7)) * 8;
  const int pq1 = ((1 * 4 + quad) ^ (l15 & 7)) * 8;

  for (int kk = 0; kk < NC; kk += BK) {
    if (kk) {
      __syncthreads();
#pragma unroll
      for (int i = 0; i < 4; ++i)
        __builtin_amdgcn_global_load_lds(
            (const __attribute__((address_space(1))) u32*)(gA + kk + (size_t)(64 * i) * NC),
            (__attribute__((address_space(3))) u32*)(As + 4096 * i + ldst), 16, 0, 0);
#pragma unroll
      for (int i = 0; i < 2; ++i)
        __builtin_amdgcn_global_load_lds(
            (const __attribute__((address_space(1))) u32*)(gB + kk + (size_t)(64 * i) * NC),
            (__attribute__((address_space(3))) u32*)(Bs + 4096 * i + ldst), 16, 0, 0);
      __syncthreads();
    }

#pragma unroll
    for (int kq = 0; kq < 2; ++kq) {
      const int pq = kq ? pq1 : pq0;
      short8 xf[4], wf[4];
#pragma unroll
      for (int ni = 0; ni < 4; ++ni)       // A-frag: x rows (n)
        xf[ni] = *(const short8*)&Bs[(wn + ni * 16 + l15) * BK + pq];
#pragma unroll
      for (int mi = 0; mi < 4; ++mi)       // B-frag: Wv rows (d)
        wf[mi] = *(const short8*)&As[(wd + mi * 16 + l15) * BK + pq];
#pragma unroll
      for (int ni = 0; ni < 4; ++ni)
#pragma unroll
        for (int mi = 0; mi < 4; ++mi)
          acc[ni][mi] = __builtin_amdgcn_mfma_f32_16x16x32_bf16(xf[ni], wf[mi],
                                                                acc[ni][mi], 0, 0, 0);
    }
  }

  // ---- epilogue: D row = n (quad*4+r), col = d (l15) -> f32x4 stores ----
#pragma unroll
  for (int mi = 0; mi < 4; ++mi) {
    const int d = wd + mi * 16 + l15;
    const float cx = sctx[d];
    float* op = out + (size_t)(b * NC + d) * NN + n0 + wn + quad * 4;
#pragma unroll
    for (int ni = 0; ni < 4; ++ni) {
      f32x4 v = acc[ni][mi];
      v[0] = fmaxf(v[0], 0.f) * cx;
      v[1] = fmaxf(v[1], 0.f) * cx;
      v[2] = fmaxf(v[2], 0.f) * cx;
      v[3] = fmaxf(v[3], 0.f) * cx;
      __builtin_nontemporal_store(v, (f32x4*)(op + ni * 16));
    }
  }
}

// ---------------------------------------------------------------------------
extern "C" void kernel_launch(void* const* d_in, const int* in_sizes, int n_in,
                              void* d_out, int out_size, void* d_ws, size_t ws_size,
                              hipStream_t stream) {
  const float* x = (const float*)d_in[0];
  const float* W = (const float*)d_in[1];
  float* out = (float*)d_out;

  char* ws = (char*)d_ws;
  u16* xbT    = (u16*)ws;                                 // 33,554,432 B
  float* pacc = (float*)(ws + 33554432);                  //  1,048,576 B
  float* pm   = (float*)(ws + 34603008);                  //      4,096 B
  float* pl   = (float*)(ws + 34607104);                  //      4,096 B
  u16* wvb    = (u16*)(ws + 34611200);                    //    131,072 B

  k_fuse1<<<dim3(64, 16), 256, 0, stream>>>(x, W, xbT, wvb, pm, pl, pacc);
  k_gemm<<<dim3(32, 16), 512, 0, stream>>>(xbT, wvb, W, pm, pl, pacc, out);
}